// Round 1
// baseline (2603.059 us; speedup 1.0000x reference)
//
#include <hip/hip_runtime.h>
#include <stdint.h>

#define DIM_    1024
#define INTER_  512
#define T_TOK   32768

typedef short bf16x4 __attribute__((ext_vector_type(4)));
typedef short bf16x8 __attribute__((ext_vector_type(8)));
typedef float f32x4  __attribute__((ext_vector_type(4)));

__device__ __forceinline__ unsigned short f2bf(float f) {
  union { float f; unsigned u; } v; v.f = f;
  return (unsigned short)((v.u + 0x7FFFu + ((v.u >> 16) & 1u)) >> 16);
}
__device__ __forceinline__ unsigned f2bf2(float a, float b) {
  union { float f; unsigned u; } va, vb; va.f = a; vb.f = b;
  unsigned ra = (va.u + 0x7FFFu + ((va.u >> 16) & 1u)) >> 16;
  unsigned rb = (vb.u + 0x7FFFu + ((vb.u >> 16) & 1u)) >> 16;
  return ra | (rb << 16);
}
__device__ __forceinline__ int xorB(int j) { return (j & 7) ^ ((j >> 3) & 7); }

// ---------------------------------------------------------------- gate ----
// One wave per token. Logits + softmax in fp64 (match numpy golden ref as
// closely as possible so top-k selection doesn't flip). Lanes 0..31 = experts,
// lane halves split the K=1024 dot. Serial grouped top-k on lane 0 (strict >
// keeps lowest index on ties, matching jax.lax.top_k stable order).
__global__ __launch_bounds__(256) void gate_kernel(
    const float* __restrict__ x, const float* __restrict__ gw,
    const float* __restrict__ gb, int* __restrict__ idx, float* __restrict__ wts) {
  __shared__ double s_sc[4][32];
  __shared__ double s_gs[4][8];
  const int wid = threadIdx.x >> 6, lane = threadIdx.x & 63;
  const int t = blockIdx.x * 4 + wid;
  const int e = lane & 31, half = lane >> 5;
  const float* xr  = x  + (size_t)t * DIM_ + half * 512;
  const float* gwp = gw + (size_t)half * 512 * 32 + e;
  double a0 = 0, a1 = 0, a2 = 0, a3 = 0;
  for (int k = 0; k < 512; k += 4) {
    float4 xv = *(const float4*)(xr + k);
    a0 += (double)xv.x * (double)gwp[(k + 0) * 32];
    a1 += (double)xv.y * (double)gwp[(k + 1) * 32];
    a2 += (double)xv.z * (double)gwp[(k + 2) * 32];
    a3 += (double)xv.w * (double)gwp[(k + 3) * 32];
  }
  double lg = (a0 + a1) + (a2 + a3);
  lg += __shfl_xor(lg, 32);
  lg += (double)gb[e];
  double m = lg;
  #pragma unroll
  for (int d = 1; d < 32; d <<= 1) m = fmax(m, __shfl_xor(m, d));
  double ex = exp(lg - m);
  double ssum = ex;
  #pragma unroll
  for (int d = 1; d < 32; d <<= 1) ssum += __shfl_xor(ssum, d);
  double sc = ex / ssum;
  // top-2 sum within each group of 4 experts (quad shuffle reduce)
  double p  = __shfl_xor(sc, 1);
  double m1 = fmax(sc, p), n1 = fmin(sc, p);
  double m2 = __shfl_xor(m1, 2), n2 = __shfl_xor(n1, 2);
  double gs = (m1 >= m2) ? (m1 + fmax(n1, m2)) : (m2 + fmax(n2, m1));
  if (lane < 32) {
    s_sc[wid][e] = sc;
    if ((e & 3) == 0) s_gs[wid][e >> 2] = gs;
  }
  __syncthreads();
  if (lane == 0) {
    unsigned kmask = 0;
    for (int it = 0; it < 4; ++it) {
      int bg = 0; double bv = -1.0;
      for (int g = 0; g < 8; ++g)
        if (!((kmask >> g) & 1u) && s_gs[wid][g] > bv) { bv = s_gs[wid][g]; bg = g; }
      kmask |= 1u << bg;
    }
    unsigned umask = 0;
    for (int slot = 0; slot < 4; ++slot) {
      int be = 0; double bv = -1.0;
      for (int ee = 0; ee < 32; ++ee)
        if (((kmask >> (ee >> 2)) & 1u) && !((umask >> ee) & 1u) && s_sc[wid][ee] > bv) {
          bv = s_sc[wid][ee]; be = ee;
        }
      umask |= 1u << be;
      idx[t * 4 + slot] = be;
      wts[t * 4 + slot] = (float)bv;
    }
  }
}

// ------------------------------------------------- dispatch bookkeeping ----
// meta: [0..31] counts  [32..63] cursors  [64..96] offsets  [97] ntiles
//       [128..1183] tile_expert  [1184..2239] tile_m0
__global__ __launch_bounds__(256) void count_kernel(const int* __restrict__ idx,
                                                    int* __restrict__ meta) {
  int i = blockIdx.x * 256 + threadIdx.x;
  atomicAdd(&meta[idx[i]], 1);
}

__global__ void scan_kernel(int* __restrict__ meta) {
  if (threadIdx.x == 0) {
    int acc = 0, nt = 0;
    for (int e = 0; e < 32; ++e) {
      int c = meta[e];
      meta[64 + e] = acc;
      meta[32 + e] = acc;
      for (int m0 = 0; m0 < c; m0 += 128) { meta[128 + nt] = e; meta[1184 + nt] = m0; ++nt; }
      acc += c;
    }
    meta[96] = acc;
    meta[97] = nt;
  }
}

__global__ __launch_bounds__(256) void scatter_kernel(
    const int* __restrict__ idx, const float* __restrict__ wts,
    int* __restrict__ meta, int* __restrict__ tok, float* __restrict__ wtl) {
  int i = blockIdx.x * 256 + threadIdx.x;
  int e = idx[i];
  int p = atomicAdd(&meta[32 + e], 1);
  tok[p] = i >> 2;
  wtl[p] = wts[i];
}

// --------------------------------------------------------- shared GEMM1 ----
// Hs[t][j] = silu(x@sw1 + sb1) * (x@sw3 + sb3), bf16.  BM=128 BN=64 BK=32.
__global__ __launch_bounds__(256) void s1_kernel(
    const float* __restrict__ x, const float* __restrict__ sw1, const float* __restrict__ sb1,
    const float* __restrict__ sw3, const float* __restrict__ sb3,
    unsigned short* __restrict__ Hs) {
  __shared__ char lds[16384];
  char* ldsA  = lds;           // [128][32] bf16, 16B slots ^ (row&3)
  char* ldsB1 = lds + 8192;    // [64][32] bf16 (B^T), 8B slots ^ xorB(j)
  char* ldsB3 = lds + 12288;
  const int n0 = blockIdx.x * 64;
  const int m0 = blockIdx.y * 128;
  const int tid = threadIdx.x, lane = tid & 63;
  const int wm = (tid >> 6) >> 1, wn = (tid >> 6) & 1;

  const int sr = tid >> 1, sh = tid & 1;
  const float* asrc = x + (size_t)(m0 + sr) * DIM_ + sh * 16;
  const int as0 = ((2 * sh) ^ (sr & 3)) << 4, as1 = ((2 * sh + 1) ^ (sr & 3)) << 4;
  char* aw = ldsA + sr * 64;

  const int bj0 = (tid & 15) * 4, bm = tid >> 4;      // bm 0..15 -> k pair
  const int bk0 = bm * 2, bslot = bm >> 1, bko = (bm & 1) * 4;
  const float* b1s = sw1 + (size_t)bk0 * 1024 + n0 + bj0;
  const float* b3s = sw3 + (size_t)bk0 * 1024 + n0 + bj0;

  const int g = lane >> 4;
  const int aro = (wm * 64 + (lane & 15)) * 64 + ((g ^ (lane & 3)) << 4);
  int bofs[2];
  #pragma unroll
  for (int ni = 0; ni < 2; ++ni) {
    int j = wn * 32 + ni * 16 + (lane & 15);
    bofs[ni] = j * 64 + (((2 * g) ^ xorB(j)) << 3);
  }

  f32x4 acc1[4][2], acc3[4][2];
  const f32x4 zz = {0.f, 0.f, 0.f, 0.f};
  #pragma unroll
  for (int mi = 0; mi < 4; ++mi)
    #pragma unroll
    for (int ni = 0; ni < 2; ++ni) { acc1[mi][ni] = zz; acc3[mi][ni] = zz; }

  for (int kb = 0; kb < 1024; kb += 32) {
    __syncthreads();
    {
      const float4* ap = (const float4*)(asrc + kb);
      float4 f0 = ap[0], f1 = ap[1], f2v = ap[2], f3v = ap[3];
      uint4 u0, u1;
      u0.x = f2bf2(f0.x, f0.y);  u0.y = f2bf2(f0.z, f0.w);
      u0.z = f2bf2(f1.x, f1.y);  u0.w = f2bf2(f1.z, f1.w);
      u1.x = f2bf2(f2v.x, f2v.y); u1.y = f2bf2(f2v.z, f2v.w);
      u1.z = f2bf2(f3v.x, f3v.y); u1.w = f2bf2(f3v.z, f3v.w);
      *(uint4*)(aw + as0) = u0;
      *(uint4*)(aw + as1) = u1;
    }
    {
      const float* bp = b1s + (size_t)kb * 1024;
      float4 r0 = *(const float4*)bp;
      float4 r1 = *(const float4*)(bp + 1024);
      #pragma unroll
      for (int jj = 0; jj < 4; ++jj) {
        int j = bj0 + jj;
        unsigned v = f2bf2(((const float*)&r0)[jj], ((const float*)&r1)[jj]);
        *(unsigned*)(ldsB1 + j * 64 + ((bslot ^ xorB(j)) << 3) + bko) = v;
      }
      const float* cp = b3s + (size_t)kb * 1024;
      float4 q0 = *(const float4*)cp;
      float4 q1 = *(const float4*)(cp + 1024);
      #pragma unroll
      for (int jj = 0; jj < 4; ++jj) {
        int j = bj0 + jj;
        unsigned v = f2bf2(((const float*)&q0)[jj], ((const float*)&q1)[jj]);
        *(unsigned*)(ldsB3 + j * 64 + ((bslot ^ xorB(j)) << 3) + bko) = v;
      }
    }
    __syncthreads();
    bf16x8 af[4];
    #pragma unroll
    for (int mi = 0; mi < 4; ++mi) af[mi] = *(const bf16x8*)(ldsA + aro + mi * 1024);
    #pragma unroll
    for (int ni = 0; ni < 2; ++ni) {
      bf16x4 lo = *(const bf16x4*)(ldsB1 + bofs[ni]);
      bf16x4 hi = *(const bf16x4*)(ldsB1 + (bofs[ni] ^ 8));
      bf16x8 bv = __builtin_shufflevector(lo, hi, 0, 1, 2, 3, 4, 5, 6, 7);
      #pragma unroll
      for (int mi = 0; mi < 4; ++mi)
        acc1[mi][ni] = __builtin_amdgcn_mfma_f32_16x16x32_bf16(af[mi], bv, acc1[mi][ni], 0, 0, 0);
      bf16x4 lo3 = *(const bf16x4*)(ldsB3 + bofs[ni]);
      bf16x4 hi3 = *(const bf16x4*)(ldsB3 + (bofs[ni] ^ 8));
      bf16x8 bv3 = __builtin_shufflevector(lo3, hi3, 0, 1, 2, 3, 4, 5, 6, 7);
      #pragma unroll
      for (int mi = 0; mi < 4; ++mi)
        acc3[mi][ni] = __builtin_amdgcn_mfma_f32_16x16x32_bf16(af[mi], bv3, acc3[mi][ni], 0, 0, 0);
    }
  }
  #pragma unroll
  for (int ni = 0; ni < 2; ++ni) {
    int col = n0 + wn * 32 + ni * 16 + (lane & 15);
    float bb1 = sb1[col], bb3 = sb3[col];
    #pragma unroll
    for (int mi = 0; mi < 4; ++mi) {
      int rb = wm * 64 + mi * 16 + ((lane >> 4) << 2);
      #pragma unroll
      for (int r = 0; r < 4; ++r) {
        int row = m0 + rb + r;
        float v1 = acc1[mi][ni][r] + bb1;
        float v3 = acc3[mi][ni][r] + bb3;
        float h = (v1 / (1.f + __expf(-v1))) * v3;
        Hs[(size_t)row * 1024 + col] = f2bf(h);
      }
    }
  }
}

// --------------------------------------------------------- shared GEMM2 ----
// out[t][c] = Hs @ sw2 + sb2 (plain store; initializes d_out). BM=128 BN=128.
__global__ __launch_bounds__(256) void s2_kernel(
    const unsigned short* __restrict__ Hs, const float* __restrict__ sw2,
    const float* __restrict__ sb2, float* __restrict__ out) {
  __shared__ char lds[16384];
  char* ldsA = lds; char* ldsB = lds + 8192;
  const int n0 = blockIdx.x * 128;
  const int m0 = blockIdx.y * 128;
  const int tid = threadIdx.x, lane = tid & 63;
  const int wm = (tid >> 6) >> 1, wn = (tid >> 6) & 1;
  const int sr = tid >> 1, sh = tid & 1;
  const unsigned short* asrc = Hs + (size_t)(m0 + sr) * 1024 + sh * 16;
  const int as0 = ((2 * sh) ^ (sr & 3)) << 4, as1 = ((2 * sh + 1) ^ (sr & 3)) << 4;
  char* aw = ldsA + sr * 64;
  const int bj0 = (tid & 31) * 4, bkq = tid >> 5;     // bkq 0..7 -> k quad
  const float* bsrc = sw2 + (size_t)bkq * 4 * 1024 + n0 + bj0;
  const int g = lane >> 4;
  const int aro = (wm * 64 + (lane & 15)) * 64 + ((g ^ (lane & 3)) << 4);
  int bofs[4];
  #pragma unroll
  for (int ni = 0; ni < 4; ++ni) {
    int j = wn * 64 + ni * 16 + (lane & 15);
    bofs[ni] = j * 64 + (((2 * g) ^ xorB(j)) << 3);
  }
  f32x4 acc[4][4];
  const f32x4 zz = {0.f, 0.f, 0.f, 0.f};
  #pragma unroll
  for (int mi = 0; mi < 4; ++mi)
    #pragma unroll
    for (int ni = 0; ni < 4; ++ni) acc[mi][ni] = zz;

  for (int kb = 0; kb < 1024; kb += 32) {
    __syncthreads();
    {
      const uint4* ap = (const uint4*)(asrc + kb);
      uint4 u0 = ap[0], u1 = ap[1];
      *(uint4*)(aw + as0) = u0;
      *(uint4*)(aw + as1) = u1;
    }
    {
      const float* bp = bsrc + (size_t)kb * 1024;
      float4 r0 = *(const float4*)bp;
      float4 r1 = *(const float4*)(bp + 1024);
      float4 r2 = *(const float4*)(bp + 2048);
      float4 r3 = *(const float4*)(bp + 3072);
      #pragma unroll
      for (int jj = 0; jj < 4; ++jj) {
        int j = bj0 + jj;
        uint2 v;
        v.x = f2bf2(((const float*)&r0)[jj], ((const float*)&r1)[jj]);
        v.y = f2bf2(((const float*)&r2)[jj], ((const float*)&r3)[jj]);
        *(uint2*)(ldsB + j * 64 + ((bkq ^ xorB(j)) << 3)) = v;
      }
    }
    __syncthreads();
    bf16x8 af[4];
    #pragma unroll
    for (int mi = 0; mi < 4; ++mi) af[mi] = *(const bf16x8*)(ldsA + aro + mi * 1024);
    #pragma unroll
    for (int ni = 0; ni < 4; ++ni) {
      bf16x4 lo = *(const bf16x4*)(ldsB + bofs[ni]);
      bf16x4 hi = *(const bf16x4*)(ldsB + (bofs[ni] ^ 8));
      bf16x8 bv = __builtin_shufflevector(lo, hi, 0, 1, 2, 3, 4, 5, 6, 7);
      #pragma unroll
      for (int mi = 0; mi < 4; ++mi)
        acc[mi][ni] = __builtin_amdgcn_mfma_f32_16x16x32_bf16(af[mi], bv, acc[mi][ni], 0, 0, 0);
    }
  }
  #pragma unroll
  for (int ni = 0; ni < 4; ++ni) {
    int col = n0 + wn * 64 + ni * 16 + (lane & 15);
    float bb = sb2[col];
    #pragma unroll
    for (int mi = 0; mi < 4; ++mi) {
      int rb = m0 + wm * 64 + mi * 16 + ((lane >> 4) << 2);
      #pragma unroll
      for (int r = 0; r < 4; ++r)
        out[(size_t)(rb + r) * 1024 + col] = acc[mi][ni][r] + bb;
    }
  }
}

// --------------------------------------------------------- routed GEMM1 ----
// H[row][j] = silu(xg@w1e+b1e)*(xg@w3e+b3e) for gathered token rows.
__global__ __launch_bounds__(256) void g1_kernel(
    const float* __restrict__ x, const float* __restrict__ w1, const float* __restrict__ b1,
    const float* __restrict__ w3, const float* __restrict__ b3,
    const int* __restrict__ tok, const int* __restrict__ meta,
    unsigned short* __restrict__ H) {
  __shared__ char lds[16384];
  if ((int)blockIdx.y >= meta[97]) return;
  const int e = meta[128 + blockIdx.y], m0 = meta[1184 + blockIdx.y];
  const int off_e = meta[64 + e], nrem = meta[e] - m0;
  char* ldsA  = lds;
  char* ldsB1 = lds + 8192;
  char* ldsB3 = lds + 12288;
  const int n0 = blockIdx.x * 64;
  const int tid = threadIdx.x, lane = tid & 63;
  const int wm = (tid >> 6) >> 1, wn = (tid >> 6) & 1;

  const int sr = tid >> 1, sh = tid & 1;
  const int srow = (sr < nrem) ? sr : 0;
  const float* asrc = x + (size_t)tok[off_e + m0 + srow] * DIM_ + sh * 16;
  const int as0 = ((2 * sh) ^ (sr & 3)) << 4, as1 = ((2 * sh + 1) ^ (sr & 3)) << 4;
  char* aw = ldsA + sr * 64;

  const int bj0 = (tid & 15) * 4, bm = tid >> 4;
  const int bk0 = bm * 2, bslot = bm >> 1, bko = (bm & 1) * 4;
  const float* b1s = w1 + (size_t)e * (1024 * 512) + (size_t)bk0 * 512 + n0 + bj0;
  const float* b3s = w3 + (size_t)e * (1024 * 512) + (size_t)bk0 * 512 + n0 + bj0;

  const int g = lane >> 4;
  const int aro = (wm * 64 + (lane & 15)) * 64 + ((g ^ (lane & 3)) << 4);
  int bofs[2];
  #pragma unroll
  for (int ni = 0; ni < 2; ++ni) {
    int j = wn * 32 + ni * 16 + (lane & 15);
    bofs[ni] = j * 64 + (((2 * g) ^ xorB(j)) << 3);
  }

  f32x4 acc1[4][2], acc3[4][2];
  const f32x4 zz = {0.f, 0.f, 0.f, 0.f};
  #pragma unroll
  for (int mi = 0; mi < 4; ++mi)
    #pragma unroll
    for (int ni = 0; ni < 2; ++ni) { acc1[mi][ni] = zz; acc3[mi][ni] = zz; }

  for (int kb = 0; kb < 1024; kb += 32) {
    __syncthreads();
    {
      const float4* ap = (const float4*)(asrc + kb);
      float4 f0 = ap[0], f1 = ap[1], f2v = ap[2], f3v = ap[3];
      uint4 u0, u1;
      u0.x = f2bf2(f0.x, f0.y);  u0.y = f2bf2(f0.z, f0.w);
      u0.z = f2bf2(f1.x, f1.y);  u0.w = f2bf2(f1.z, f1.w);
      u1.x = f2bf2(f2v.x, f2v.y); u1.y = f2bf2(f2v.z, f2v.w);
      u1.z = f2bf2(f3v.x, f3v.y); u1.w = f2bf2(f3v.z, f3v.w);
      *(uint4*)(aw + as0) = u0;
      *(uint4*)(aw + as1) = u1;
    }
    {
      const float* bp = b1s + (size_t)kb * 512;
      float4 r0 = *(const float4*)bp;
      float4 r1 = *(const float4*)(bp + 512);
      #pragma unroll
      for (int jj = 0; jj < 4; ++jj) {
        int j = bj0 + jj;
        unsigned v = f2bf2(((const float*)&r0)[jj], ((const float*)&r1)[jj]);
        *(unsigned*)(ldsB1 + j * 64 + ((bslot ^ xorB(j)) << 3) + bko) = v;
      }
      const float* cp = b3s + (size_t)kb * 512;
      float4 q0 = *(const float4*)cp;
      float4 q1 = *(const float4*)(cp + 512);
      #pragma unroll
      for (int jj = 0; jj < 4; ++jj) {
        int j = bj0 + jj;
        unsigned v = f2bf2(((const float*)&q0)[jj], ((const float*)&q1)[jj]);
        *(unsigned*)(ldsB3 + j * 64 + ((bslot ^ xorB(j)) << 3) + bko) = v;
      }
    }
    __syncthreads();
    bf16x8 af[4];
    #pragma unroll
    for (int mi = 0; mi < 4; ++mi) af[mi] = *(const bf16x8*)(ldsA + aro + mi * 1024);
    #pragma unroll
    for (int ni = 0; ni < 2; ++ni) {
      bf16x4 lo = *(const bf16x4*)(ldsB1 + bofs[ni]);
      bf16x4 hi = *(const bf16x4*)(ldsB1 + (bofs[ni] ^ 8));
      bf16x8 bv = __builtin_shufflevector(lo, hi, 0, 1, 2, 3, 4, 5, 6, 7);
      #pragma unroll
      for (int mi = 0; mi < 4; ++mi)
        acc1[mi][ni] = __builtin_amdgcn_mfma_f32_16x16x32_bf16(af[mi], bv, acc1[mi][ni], 0, 0, 0);
      bf16x4 lo3 = *(const bf16x4*)(ldsB3 + bofs[ni]);
      bf16x4 hi3 = *(const bf16x4*)(ldsB3 + (bofs[ni] ^ 8));
      bf16x8 bv3 = __builtin_shufflevector(lo3, hi3, 0, 1, 2, 3, 4, 5, 6, 7);
      #pragma unroll
      for (int mi = 0; mi < 4; ++mi)
        acc3[mi][ni] = __builtin_amdgcn_mfma_f32_16x16x32_bf16(af[mi], bv3, acc3[mi][ni], 0, 0, 0);
    }
  }
  #pragma unroll
  for (int ni = 0; ni < 2; ++ni) {
    int col = n0 + wn * 32 + ni * 16 + (lane & 15);
    float bb1 = b1[e * 512 + col], bb3 = b3[e * 512 + col];
    #pragma unroll
    for (int mi = 0; mi < 4; ++mi) {
      int rb = wm * 64 + mi * 16 + ((lane >> 4) << 2);
      #pragma unroll
      for (int r = 0; r < 4; ++r) {
        int row = rb + r;
        if (row < nrem) {
          float v1 = acc1[mi][ni][r] + bb1;
          float v3 = acc3[mi][ni][r] + bb3;
          float h = (v1 / (1.f + __expf(-v1))) * v3;
          H[(size_t)(off_e + m0 + row) * 512 + col] = f2bf(h);
        }
      }
    }
  }
}

// --------------------------------------------------------- routed GEMM2 ----
// out[tok] += w * (H@w2e + b2e), atomic scatter-add.
__global__ __launch_bounds__(256) void g2_kernel(
    const unsigned short* __restrict__ H, const float* __restrict__ w2,
    const float* __restrict__ b2, const int* __restrict__ tok,
    const float* __restrict__ wtl, const int* __restrict__ meta,
    float* __restrict__ out) {
  __shared__ char lds[16384];
  if ((int)blockIdx.y >= meta[97]) return;
  const int e = meta[128 + blockIdx.y], m0 = meta[1184 + blockIdx.y];
  const int off_e = meta[64 + e], nrem = meta[e] - m0;
  char* ldsA = lds; char* ldsB = lds + 8192;
  const int n0 = blockIdx.x * 128;
  const int tid = threadIdx.x, lane = tid & 63;
  const int wm = (tid >> 6) >> 1, wn = (tid >> 6) & 1;
  const int sr = tid >> 1, sh = tid & 1;
  const int srow = (sr < nrem) ? sr : 0;
  const unsigned short* asrc = H + (size_t)(off_e + m0 + srow) * 512 + sh * 16;
  const int as0 = ((2 * sh) ^ (sr & 3)) << 4, as1 = ((2 * sh + 1) ^ (sr & 3)) << 4;
  char* aw = ldsA + sr * 64;
  const int bj0 = (tid & 31) * 4, bkq = tid >> 5;
  const float* bsrc = w2 + (size_t)e * (512 * 1024) + (size_t)bkq * 4 * 1024 + n0 + bj0;
  const int g = lane >> 4;
  const int aro = (wm * 64 + (lane & 15)) * 64 + ((g ^ (lane & 3)) << 4);
  int bofs[4];
  #pragma unroll
  for (int ni = 0; ni < 4; ++ni) {
    int j = wn * 64 + ni * 16 + (lane & 15);
    bofs[ni] = j * 64 + (((2 * g) ^ xorB(j)) << 3);
  }
  f32x4 acc[4][4];
  const f32x4 zz = {0.f, 0.f, 0.f, 0.f};
  #pragma unroll
  for (int mi = 0; mi < 4; ++mi)
    #pragma unroll
    for (int ni = 0; ni < 4; ++ni) acc[mi][ni] = zz;

  for (int kb = 0; kb < 512; kb += 32) {
    __syncthreads();
    {
      const uint4* ap = (const uint4*)(asrc + kb);
      uint4 u0 = ap[0], u1 = ap[1];
      *(uint4*)(aw + as0) = u0;
      *(uint4*)(aw + as1) = u1;
    }
    {
      const float* bp = bsrc + (size_t)kb * 1024;
      float4 r0 = *(const float4*)bp;
      float4 r1 = *(const float4*)(bp + 1024);
      float4 r2 = *(const float4*)(bp + 2048);
      float4 r3 = *(const float4*)(bp + 3072);
      #pragma unroll
      for (int jj = 0; jj < 4; ++jj) {
        int j = bj0 + jj;
        uint2 v;
        v.x = f2bf2(((const float*)&r0)[jj], ((const float*)&r1)[jj]);
        v.y = f2bf2(((const float*)&r2)[jj], ((const float*)&r3)[jj]);
        *(uint2*)(ldsB + j * 64 + ((bkq ^ xorB(j)) << 3)) = v;
      }
    }
    __syncthreads();
    bf16x8 af[4];
    #pragma unroll
    for (int mi = 0; mi < 4; ++mi) af[mi] = *(const bf16x8*)(ldsA + aro + mi * 1024);
    #pragma unroll
    for (int ni = 0; ni < 4; ++ni) {
      bf16x4 lo = *(const bf16x4*)(ldsB + bofs[ni]);
      bf16x4 hi = *(const bf16x4*)(ldsB + (bofs[ni] ^ 8));
      bf16x8 bv = __builtin_shufflevector(lo, hi, 0, 1, 2, 3, 4, 5, 6, 7);
      #pragma unroll
      for (int mi = 0; mi < 4; ++mi)
        acc[mi][ni] = __builtin_amdgcn_mfma_f32_16x16x32_bf16(af[mi], bv, acc[mi][ni], 0, 0, 0);
    }
  }
  #pragma unroll
  for (int ni = 0; ni < 4; ++ni) {
    int col = n0 + wn * 64 + ni * 16 + (lane & 15);
    float bb = b2[e * 1024 + col];
    #pragma unroll
    for (int mi = 0; mi < 4; ++mi) {
      int rb = wm * 64 + mi * 16 + ((lane >> 4) << 2);
      #pragma unroll
      for (int r = 0; r < 4; ++r) {
        int row = rb + r;
        if (row < nrem) {
          int gi = off_e + m0 + row;
          atomicAdd(out + (size_t)tok[gi] * 1024 + col, (acc[mi][ni][r] + bb) * wtl[gi]);
        }
      }
    }
  }
}

// ------------------------------------------------------------------ host ----
extern "C" void kernel_launch(void* const* d_in, const int* in_sizes, int n_in,
                              void* d_out, int out_size, void* d_ws, size_t ws_size,
                              hipStream_t stream) {
  const float* x   = (const float*)d_in[0];
  const float* gw  = (const float*)d_in[1];
  const float* gb  = (const float*)d_in[2];
  const float* w1  = (const float*)d_in[3];
  const float* b1  = (const float*)d_in[4];
  const float* w3  = (const float*)d_in[5];
  const float* b3  = (const float*)d_in[6];
  const float* w2  = (const float*)d_in[7];
  const float* b2  = (const float*)d_in[8];
  const float* sw1 = (const float*)d_in[9];
  const float* sb1 = (const float*)d_in[10];
  const float* sw3 = (const float*)d_in[11];
  const float* sb3 = (const float*)d_in[12];
  const float* sw2 = (const float*)d_in[13];
  const float* sb2 = (const float*)d_in[14];
  float* out = (float*)d_out;
  char* ws = (char*)d_ws;

  const size_t OFF_IDX  = 134217728;           // H: 131072*512 bf16 (reused as Hs 32768*1024)
  const size_t OFF_WTS  = OFF_IDX + 524288;
  const size_t OFF_TOK  = OFF_WTS + 524288;
  const size_t OFF_WTL  = OFF_TOK + 524288;
  const size_t OFF_META = OFF_WTL + 524288;
  if (ws_size < OFF_META + 8960) return;       // loud failure if ws too small

  unsigned short* H = (unsigned short*)ws;
  int*   idx  = (int*)(ws + OFF_IDX);
  float* wts  = (float*)(ws + OFF_WTS);
  int*   tokl = (int*)(ws + OFF_TOK);
  float* wtl  = (float*)(ws + OFF_WTL);
  int*   meta = (int*)(ws + OFF_META);

  hipMemsetAsync(meta, 0, 128, stream);  // counts only; scan rewrites the rest
  gate_kernel<<<dim3(8192), dim3(256), 0, stream>>>(x, gw, gb, idx, wts);
  count_kernel<<<dim3(512), dim3(256), 0, stream>>>(idx, meta);
  scan_kernel<<<dim3(1), dim3(64), 0, stream>>>(meta);
  scatter_kernel<<<dim3(512), dim3(256), 0, stream>>>(idx, wts, meta, tokl, wtl);
  s1_kernel<<<dim3(16, 256), dim3(256), 0, stream>>>(x, sw1, sb1, sw3, sb3, H);
  s2_kernel<<<dim3(8, 256), dim3(256), 0, stream>>>(H, sw2, sb2, out);
  g1_kernel<<<dim3(8, 1056), dim3(256), 0, stream>>>(x, w1, b1, w3, b3, tokl, meta, H);
  g2_kernel<<<dim3(8, 1056), dim3(256), 0, stream>>>(H, w2, b2, tokl, wtl, meta, out);
}

// Round 2
// 1873.039 us; speedup vs baseline: 1.3898x; 1.3898x over previous
//
#include <hip/hip_runtime.h>
#include <stdint.h>

#define DIM_    1024
#define INTER_  512

typedef short bf16x4 __attribute__((ext_vector_type(4)));
typedef short bf16x8 __attribute__((ext_vector_type(8)));
typedef float f32x4  __attribute__((ext_vector_type(4)));

__device__ __forceinline__ unsigned short f2bf(float f) {
  union { float f; unsigned u; } v; v.f = f;
  return (unsigned short)((v.u + 0x7FFFu + ((v.u >> 16) & 1u)) >> 16);
}
__device__ __forceinline__ unsigned f2bf2(float a, float b) {
  union { float f; unsigned u; } va, vb; va.f = a; vb.f = b;
  unsigned ra = (va.u + 0x7FFFu + ((va.u >> 16) & 1u)) >> 16;
  unsigned rb = (vb.u + 0x7FFFu + ((vb.u >> 16) & 1u)) >> 16;
  return ra | (rb << 16);
}
__device__ __forceinline__ int xorB(int j) { return (j & 7) ^ ((j >> 3) & 7); }

// global -> LDS direct DMA, 16B per lane. lds dest must be wave-uniform base.
__device__ __forceinline__ void gl16(const void* g, void* l) {
  __builtin_amdgcn_global_load_lds(
      (const __attribute__((address_space(1))) unsigned int*)g,
      (__attribute__((address_space(3))) unsigned int*)l, 16, 0, 0);
}

// ---------------------------------------------------------------- gate ----
__global__ __launch_bounds__(256) void gate_kernel(
    const float* __restrict__ x, const float* __restrict__ gw,
    const float* __restrict__ gb, int* __restrict__ idx, float* __restrict__ wts) {
  __shared__ double s_sc[4][32];
  __shared__ double s_gs[4][8];
  const int wid = threadIdx.x >> 6, lane = threadIdx.x & 63;
  const int t = blockIdx.x * 4 + wid;
  const int e = lane & 31, half = lane >> 5;
  const float* xr  = x  + (size_t)t * DIM_ + half * 512;
  const float* gwp = gw + (size_t)half * 512 * 32 + e;
  double a0 = 0, a1 = 0, a2 = 0, a3 = 0;
  for (int k = 0; k < 512; k += 4) {
    float4 xv = *(const float4*)(xr + k);
    a0 += (double)xv.x * (double)gwp[(k + 0) * 32];
    a1 += (double)xv.y * (double)gwp[(k + 1) * 32];
    a2 += (double)xv.z * (double)gwp[(k + 2) * 32];
    a3 += (double)xv.w * (double)gwp[(k + 3) * 32];
  }
  double lg = (a0 + a1) + (a2 + a3);
  lg += __shfl_xor(lg, 32);
  lg += (double)gb[e];
  double m = lg;
  #pragma unroll
  for (int d = 1; d < 32; d <<= 1) m = fmax(m, __shfl_xor(m, d));
  double ex = exp(lg - m);
  double ssum = ex;
  #pragma unroll
  for (int d = 1; d < 32; d <<= 1) ssum += __shfl_xor(ssum, d);
  double sc = ex / ssum;
  double p  = __shfl_xor(sc, 1);
  double m1 = fmax(sc, p), n1 = fmin(sc, p);
  double m2 = __shfl_xor(m1, 2), n2 = __shfl_xor(n1, 2);
  double gs = (m1 >= m2) ? (m1 + fmax(n1, m2)) : (m2 + fmax(n2, m1));
  if (lane < 32) {
    s_sc[wid][e] = sc;
    if ((e & 3) == 0) s_gs[wid][e >> 2] = gs;
  }
  __syncthreads();
  if (lane == 0) {
    unsigned kmask = 0;
    for (int it = 0; it < 4; ++it) {
      int bg = 0; double bv = -1.0;
      for (int g = 0; g < 8; ++g)
        if (!((kmask >> g) & 1u) && s_gs[wid][g] > bv) { bv = s_gs[wid][g]; bg = g; }
      kmask |= 1u << bg;
    }
    unsigned umask = 0;
    for (int slot = 0; slot < 4; ++slot) {
      int be = 0; double bv = -1.0;
      for (int ee = 0; ee < 32; ++ee)
        if (((kmask >> (ee >> 2)) & 1u) && !((umask >> ee) & 1u) && s_sc[wid][ee] > bv) {
          bv = s_sc[wid][ee]; be = ee;
        }
      umask |= 1u << be;
      idx[t * 4 + slot] = be;
      wts[t * 4 + slot] = (float)bv;
    }
  }
}

// ------------------------------------------------- dispatch bookkeeping ----
__global__ __launch_bounds__(256) void count_kernel(const int* __restrict__ idx,
                                                    int* __restrict__ meta) {
  __shared__ int h[32];
  int tid = threadIdx.x;
  if (tid < 32) h[tid] = 0;
  __syncthreads();
  atomicAdd(&h[idx[blockIdx.x * 256 + tid]], 1);
  __syncthreads();
  if (tid < 32 && h[tid]) atomicAdd(&meta[tid], h[tid]);
}

__global__ void scan_kernel(int* __restrict__ meta) {
  int lane = threadIdx.x & 63;
  if (lane < 32) {
    int c = meta[lane];
    int pre = c;
    #pragma unroll
    for (int d = 1; d < 32; d <<= 1) { int t = __shfl_up(pre, d); if (lane >= d) pre += t; }
    int excl = pre - c;
    meta[64 + lane] = excl;
    meta[32 + lane] = excl;
    int nt = (c + 127) >> 7;
    int ntp = nt;
    #pragma unroll
    for (int d = 1; d < 32; d <<= 1) { int t = __shfl_up(ntp, d); if (lane >= d) ntp += t; }
    int ntExcl = ntp - nt;
    for (int k = 0; k < nt; ++k) { meta[128 + ntExcl + k] = lane; meta[1184 + ntExcl + k] = k << 7; }
    if (lane == 31) { meta[96] = excl + c; meta[97] = ntExcl + nt; }
  }
}

__global__ __launch_bounds__(256) void scatter_kernel(
    const int* __restrict__ idx, const float* __restrict__ wts,
    int* __restrict__ meta, int* __restrict__ tok, float* __restrict__ wtl) {
  int i = blockIdx.x * 256 + threadIdx.x;
  int lane = threadIdx.x & 63;
  int e = idx[i];
  unsigned long long m = ~0ull;
  #pragma unroll
  for (int b = 0; b < 5; ++b) {
    unsigned long long vote = __ballot((e >> b) & 1);
    m &= ((e >> b) & 1) ? vote : ~vote;
  }
  int leader = __ffsll((long long)m) - 1;
  int rank = __popcll(m & ((1ull << lane) - 1));
  int base = 0;
  if (lane == leader) base = atomicAdd(&meta[32 + e], (int)__popcll(m));
  base = __shfl(base, leader);
  int p = base + rank;
  tok[p] = i >> 2;
  wtl[p] = wts[i];
}

// ----------------------------------------------------------- repacking ----
// x fp32 -> bf16 row-major
__global__ __launch_bounds__(256) void cvt_x_kernel(const float* __restrict__ x,
                                                    unsigned short* __restrict__ xb) {
  size_t i = ((size_t)blockIdx.x * 256 + threadIdx.x) * 8;
  float4 f0 = *(const float4*)(x + i);
  float4 f1 = *(const float4*)(x + i + 4);
  uint4 o;
  o.x = f2bf2(f0.x, f0.y); o.y = f2bf2(f0.z, f0.w);
  o.z = f2bf2(f1.x, f1.y); o.w = f2bf2(f1.z, f1.w);
  *(uint4*)(xb + i) = o;
}

// weight [e][K][N] fp32 -> bf16 LDS-image tiles: tile=(e,nt,kq) 4KB,
// col j in tile at j*64B, 8B slot u = q ^ xorB(j) holds k=kb+4q..+3.
// one wave per tile: lane = col, writes its full 64B.
__global__ __launch_bounds__(256) void repack_kernel(
    const float* __restrict__ src, unsigned short* __restrict__ dst,
    int K, int N, int tilesPerMat) {
  const int w = blockIdx.x * 4 + (threadIdx.x >> 6);
  const int l = threadIdx.x & 63;
  const int e = w / tilesPerMat, rem = w % tilesPerMat;
  const int kSteps = K >> 5;
  const int nt = rem / kSteps, kq = rem % kSteps;
  const float* s = src + (size_t)e * K * N + (size_t)(kq * 32) * N + nt * 64 + l;
  float v[32];
  #pragma unroll
  for (int kk = 0; kk < 32; ++kk) v[kk] = s[(size_t)kk * N];
  char* d = (char*)dst + (size_t)w * 4096 + l * 64;
  const int xb_ = xorB(l);
  #pragma unroll
  for (int q = 0; q < 8; ++q) {
    uint2 o;
    o.x = f2bf2(v[4 * q + 0], v[4 * q + 1]);
    o.y = f2bf2(v[4 * q + 2], v[4 * q + 3]);
    *(uint2*)(d + ((q ^ xb_) << 3)) = o;
  }
}

// --------------------------------------------------------- shared GEMM1 ----
// BM=128 BN=64 BK=32, dual-B (sw1,sw3), all staging via global_load_lds.
__global__ __launch_bounds__(256) void s1_kernel(
    const unsigned short* __restrict__ xb, const unsigned short* __restrict__ b1i,
    const unsigned short* __restrict__ b3i, const float* __restrict__ sb1,
    const float* __restrict__ sb3, unsigned short* __restrict__ Hs) {
  __shared__ char lds[16384];
  char* ldsA  = lds;
  char* ldsB1 = lds + 8192;
  char* ldsB3 = lds + 12288;
  const int n0 = blockIdx.x * 64;
  const int m0 = blockIdx.y * 128;
  const int tid = threadIdx.x, lane = tid & 63, wave = tid >> 6;
  const int wm = wave >> 1, wn = wave & 1;

  const int r0 = tid >> 2, s0 = tid & 3;
  const int vrw = (r0 & 3) ^ ((r0 >> 2) & 1);
  const char* a0 = (const char*)xb + (size_t)(m0 + r0) * 2048 + ((s0 ^ vrw) << 4);
  const char* a1 = (const char*)xb + (size_t)(m0 + r0 + 64) * 2048 + ((s0 ^ vrw) << 4);
  const char* b1p = (const char*)b1i + (size_t)(blockIdx.x * 32) * 4096 + tid * 16;
  const char* b3p = (const char*)b3i + (size_t)(blockIdx.x * 32) * 4096 + tid * 16;
  char* dA0 = ldsA + wave * 1024;
  char* dA1 = ldsA + 4096 + wave * 1024;
  char* dB1 = ldsB1 + wave * 1024;
  char* dB3 = ldsB3 + wave * 1024;

  const int g = lane >> 4;
  const int vfr = (lane & 3) ^ ((lane >> 2) & 1);
  const int aro = (wm * 64 + (lane & 15)) * 64 + ((g ^ vfr) << 4);
  int bofs[2];
  #pragma unroll
  for (int ni = 0; ni < 2; ++ni) {
    int j = wn * 32 + ni * 16 + (lane & 15);
    bofs[ni] = j * 64 + (((2 * g) ^ xorB(j)) << 3);
  }

  f32x4 acc1[4][2], acc3[4][2];
  const f32x4 zz = {0.f, 0.f, 0.f, 0.f};
  #pragma unroll
  for (int mi = 0; mi < 4; ++mi)
    #pragma unroll
    for (int ni = 0; ni < 2; ++ni) { acc1[mi][ni] = zz; acc3[mi][ni] = zz; }

  for (int kq = 0; kq < 32; ++kq) {
    __syncthreads();
    gl16(a0 + kq * 64, dA0);
    gl16(a1 + kq * 64, dA1);
    gl16(b1p + (size_t)kq * 4096, dB1);
    gl16(b3p + (size_t)kq * 4096, dB3);
    __syncthreads();
    bf16x8 af[4];
    #pragma unroll
    for (int mi = 0; mi < 4; ++mi) af[mi] = *(const bf16x8*)(ldsA + aro + mi * 1024);
    #pragma unroll
    for (int ni = 0; ni < 2; ++ni) {
      bf16x4 lo = *(const bf16x4*)(ldsB1 + bofs[ni]);
      bf16x4 hi = *(const bf16x4*)(ldsB1 + (bofs[ni] ^ 8));
      bf16x8 bv = __builtin_shufflevector(lo, hi, 0, 1, 2, 3, 4, 5, 6, 7);
      #pragma unroll
      for (int mi = 0; mi < 4; ++mi)
        acc1[mi][ni] = __builtin_amdgcn_mfma_f32_16x16x32_bf16(af[mi], bv, acc1[mi][ni], 0, 0, 0);
      bf16x4 lo3 = *(const bf16x4*)(ldsB3 + bofs[ni]);
      bf16x4 hi3 = *(const bf16x4*)(ldsB3 + (bofs[ni] ^ 8));
      bf16x8 bv3 = __builtin_shufflevector(lo3, hi3, 0, 1, 2, 3, 4, 5, 6, 7);
      #pragma unroll
      for (int mi = 0; mi < 4; ++mi)
        acc3[mi][ni] = __builtin_amdgcn_mfma_f32_16x16x32_bf16(af[mi], bv3, acc3[mi][ni], 0, 0, 0);
    }
  }
  #pragma unroll
  for (int ni = 0; ni < 2; ++ni) {
    int col = n0 + wn * 32 + ni * 16 + (lane & 15);
    float bb1 = sb1[col], bb3 = sb3[col];
    #pragma unroll
    for (int mi = 0; mi < 4; ++mi) {
      int rb = wm * 64 + mi * 16 + ((lane >> 4) << 2);
      #pragma unroll
      for (int r = 0; r < 4; ++r) {
        int row = m0 + rb + r;
        float v1 = acc1[mi][ni][r] + bb1;
        float v3 = acc3[mi][ni][r] + bb3;
        float h = (v1 / (1.f + __expf(-v1))) * v3;
        Hs[(size_t)row * 1024 + col] = f2bf(h);
      }
    }
  }
}

// --------------------------------------------------------- shared GEMM2 ----
// BM=128 BN=128 BK=32, K=1024. Plain store initializes d_out.
__global__ __launch_bounds__(256) void s2_kernel(
    const unsigned short* __restrict__ Hs, const unsigned short* __restrict__ b2i,
    const float* __restrict__ sb2, float* __restrict__ out) {
  __shared__ char lds[16384];
  char* ldsA = lds; char* ldsB = lds + 8192;
  const int n0 = blockIdx.x * 128;
  const int m0 = blockIdx.y * 128;
  const int tid = threadIdx.x, lane = tid & 63, wave = tid >> 6;
  const int wm = wave >> 1, wn = wave & 1;

  const int r0 = tid >> 2, s0 = tid & 3;
  const int vrw = (r0 & 3) ^ ((r0 >> 2) & 1);
  const char* a0 = (const char*)Hs + (size_t)(m0 + r0) * 2048 + ((s0 ^ vrw) << 4);
  const char* a1 = (const char*)Hs + (size_t)(m0 + r0 + 64) * 2048 + ((s0 ^ vrw) << 4);
  const char* bp0 = (const char*)b2i + (size_t)((blockIdx.x * 2 + 0) * 32) * 4096 + tid * 16;
  const char* bp1 = (const char*)b2i + (size_t)((blockIdx.x * 2 + 1) * 32) * 4096 + tid * 16;
  char* dA0 = ldsA + wave * 1024;
  char* dA1 = ldsA + 4096 + wave * 1024;
  char* dB0 = ldsB + wave * 1024;
  char* dB1 = ldsB + 4096 + wave * 1024;

  const int g = lane >> 4;
  const int vfr = (lane & 3) ^ ((lane >> 2) & 1);
  const int aro = (wm * 64 + (lane & 15)) * 64 + ((g ^ vfr) << 4);
  int bofs[4];
  #pragma unroll
  for (int ni = 0; ni < 4; ++ni) {
    int j = wn * 64 + ni * 16 + (lane & 15);
    bofs[ni] = j * 64 + (((2 * g) ^ xorB(j)) << 3);
  }
  f32x4 acc[4][4];
  const f32x4 zz = {0.f, 0.f, 0.f, 0.f};
  #pragma unroll
  for (int mi = 0; mi < 4; ++mi)
    #pragma unroll
    for (int ni = 0; ni < 4; ++ni) acc[mi][ni] = zz;

  for (int kq = 0; kq < 32; ++kq) {
    __syncthreads();
    gl16(a0 + kq * 64, dA0);
    gl16(a1 + kq * 64, dA1);
    gl16(bp0 + (size_t)kq * 4096, dB0);
    gl16(bp1 + (size_t)kq * 4096, dB1);
    __syncthreads();
    bf16x8 af[4];
    #pragma unroll
    for (int mi = 0; mi < 4; ++mi) af[mi] = *(const bf16x8*)(ldsA + aro + mi * 1024);
    #pragma unroll
    for (int ni = 0; ni < 4; ++ni) {
      bf16x4 lo = *(const bf16x4*)(ldsB + bofs[ni]);
      bf16x4 hi = *(const bf16x4*)(ldsB + (bofs[ni] ^ 8));
      bf16x8 bv = __builtin_shufflevector(lo, hi, 0, 1, 2, 3, 4, 5, 6, 7);
      #pragma unroll
      for (int mi = 0; mi < 4; ++mi)
        acc[mi][ni] = __builtin_amdgcn_mfma_f32_16x16x32_bf16(af[mi], bv, acc[mi][ni], 0, 0, 0);
    }
  }
  #pragma unroll
  for (int ni = 0; ni < 4; ++ni) {
    int col = n0 + wn * 64 + ni * 16 + (lane & 15);
    float bb = sb2[col];
    #pragma unroll
    for (int mi = 0; mi < 4; ++mi) {
      int rb = m0 + wm * 64 + mi * 16 + ((lane >> 4) << 2);
      #pragma unroll
      for (int r = 0; r < 4; ++r)
        out[(size_t)(rb + r) * 1024 + col] = acc[mi][ni][r] + bb;
    }
  }
}

// --------------------------------------------------------- routed GEMM1 ----
__global__ __launch_bounds__(256) void g1_kernel(
    const unsigned short* __restrict__ xb, const unsigned short* __restrict__ w1i,
    const unsigned short* __restrict__ w3i, const float* __restrict__ b1,
    const float* __restrict__ b3, const int* __restrict__ tok,
    const int* __restrict__ meta, unsigned short* __restrict__ H) {
  __shared__ char lds[16384];
  if ((int)blockIdx.y >= meta[97]) return;
  const int e = meta[128 + blockIdx.y], m0 = meta[1184 + blockIdx.y];
  const int off_e = meta[64 + e], nrem = meta[e] - m0;
  char* ldsA  = lds;
  char* ldsB1 = lds + 8192;
  char* ldsB3 = lds + 12288;
  const int n0 = blockIdx.x * 64;
  const int tid = threadIdx.x, lane = tid & 63, wave = tid >> 6;
  const int wm = wave >> 1, wn = wave & 1;

  const int r0 = tid >> 2, s0 = tid & 3;
  const int vrw = (r0 & 3) ^ ((r0 >> 2) & 1);
  int tr0 = tok[off_e + m0 + ((r0 < nrem) ? r0 : 0)];
  int tr1 = tok[off_e + m0 + ((r0 + 64 < nrem) ? r0 + 64 : 0)];
  const char* a0 = (const char*)xb + (size_t)tr0 * 2048 + ((s0 ^ vrw) << 4);
  const char* a1 = (const char*)xb + (size_t)tr1 * 2048 + ((s0 ^ vrw) << 4);
  const char* b1p = (const char*)w1i + (size_t)((e * 8 + blockIdx.x) * 32) * 4096 + tid * 16;
  const char* b3p = (const char*)w3i + (size_t)((e * 8 + blockIdx.x) * 32) * 4096 + tid * 16;
  char* dA0 = ldsA + wave * 1024;
  char* dA1 = ldsA + 4096 + wave * 1024;
  char* dB1 = ldsB1 + wave * 1024;
  char* dB3 = ldsB3 + wave * 1024;

  const int g = lane >> 4;
  const int vfr = (lane & 3) ^ ((lane >> 2) & 1);
  const int aro = (wm * 64 + (lane & 15)) * 64 + ((g ^ vfr) << 4);
  int bofs[2];
  #pragma unroll
  for (int ni = 0; ni < 2; ++ni) {
    int j = wn * 32 + ni * 16 + (lane & 15);
    bofs[ni] = j * 64 + (((2 * g) ^ xorB(j)) << 3);
  }

  f32x4 acc1[4][2], acc3[4][2];
  const f32x4 zz = {0.f, 0.f, 0.f, 0.f};
  #pragma unroll
  for (int mi = 0; mi < 4; ++mi)
    #pragma unroll
    for (int ni = 0; ni < 2; ++ni) { acc1[mi][ni] = zz; acc3[mi][ni] = zz; }

  for (int kq = 0; kq < 32; ++kq) {
    __syncthreads();
    gl16(a0 + kq * 64, dA0);
    gl16(a1 + kq * 64, dA1);
    gl16(b1p + (size_t)kq * 4096, dB1);
    gl16(b3p + (size_t)kq * 4096, dB3);
    __syncthreads();
    bf16x8 af[4];
    #pragma unroll
    for (int mi = 0; mi < 4; ++mi) af[mi] = *(const bf16x8*)(ldsA + aro + mi * 1024);
    #pragma unroll
    for (int ni = 0; ni < 2; ++ni) {
      bf16x4 lo = *(const bf16x4*)(ldsB1 + bofs[ni]);
      bf16x4 hi = *(const bf16x4*)(ldsB1 + (bofs[ni] ^ 8));
      bf16x8 bv = __builtin_shufflevector(lo, hi, 0, 1, 2, 3, 4, 5, 6, 7);
      #pragma unroll
      for (int mi = 0; mi < 4; ++mi)
        acc1[mi][ni] = __builtin_amdgcn_mfma_f32_16x16x32_bf16(af[mi], bv, acc1[mi][ni], 0, 0, 0);
      bf16x4 lo3 = *(const bf16x4*)(ldsB3 + bofs[ni]);
      bf16x4 hi3 = *(const bf16x4*)(ldsB3 + (bofs[ni] ^ 8));
      bf16x8 bv3 = __builtin_shufflevector(lo3, hi3, 0, 1, 2, 3, 4, 5, 6, 7);
      #pragma unroll
      for (int mi = 0; mi < 4; ++mi)
        acc3[mi][ni] = __builtin_amdgcn_mfma_f32_16x16x32_bf16(af[mi], bv3, acc3[mi][ni], 0, 0, 0);
    }
  }
  #pragma unroll
  for (int ni = 0; ni < 2; ++ni) {
    int col = n0 + wn * 32 + ni * 16 + (lane & 15);
    float bb1 = b1[e * 512 + col], bb3 = b3[e * 512 + col];
    #pragma unroll
    for (int mi = 0; mi < 4; ++mi) {
      int rb = wm * 64 + mi * 16 + ((lane >> 4) << 2);
      #pragma unroll
      for (int r = 0; r < 4; ++r) {
        int row = rb + r;
        if (row < nrem) {
          float v1 = acc1[mi][ni][r] + bb1;
          float v3 = acc3[mi][ni][r] + bb3;
          float h = (v1 / (1.f + __expf(-v1))) * v3;
          H[(size_t)(off_e + m0 + row) * 512 + col] = f2bf(h);
        }
      }
    }
  }
}

// --------------------------------------------------------- routed GEMM2 ----
__global__ __launch_bounds__(256) void g2_kernel(
    const unsigned short* __restrict__ H, const unsigned short* __restrict__ w2i,
    const float* __restrict__ b2, const int* __restrict__ tok,
    const float* __restrict__ wtl, const int* __restrict__ meta,
    float* __restrict__ out) {
  __shared__ char lds[16384];
  if ((int)blockIdx.y >= meta[97]) return;
  const int e = meta[128 + blockIdx.y], m0 = meta[1184 + blockIdx.y];
  const int off_e = meta[64 + e], nrem = meta[e] - m0;
  char* ldsA = lds; char* ldsB = lds + 8192;
  const int n0 = blockIdx.x * 128;
  const int tid = threadIdx.x, lane = tid & 63, wave = tid >> 6;
  const int wm = wave >> 1, wn = wave & 1;

  const int r0 = tid >> 2, s0 = tid & 3;
  const int vrw = (r0 & 3) ^ ((r0 >> 2) & 1);
  const char* a0 = (const char*)H + (size_t)(off_e + m0 + ((r0 < nrem) ? r0 : 0)) * 1024 + ((s0 ^ vrw) << 4);
  const char* a1 = (const char*)H + (size_t)(off_e + m0 + ((r0 + 64 < nrem) ? r0 + 64 : 0)) * 1024 + ((s0 ^ vrw) << 4);
  const char* bp0 = (const char*)w2i + (size_t)((e * 16 + blockIdx.x * 2 + 0) * 16) * 4096 + tid * 16;
  const char* bp1 = (const char*)w2i + (size_t)((e * 16 + blockIdx.x * 2 + 1) * 16) * 4096 + tid * 16;
  char* dA0 = ldsA + wave * 1024;
  char* dA1 = ldsA + 4096 + wave * 1024;
  char* dB0 = ldsB + wave * 1024;
  char* dB1 = ldsB + 4096 + wave * 1024;

  const int g = lane >> 4;
  const int vfr = (lane & 3) ^ ((lane >> 2) & 1);
  const int aro = (wm * 64 + (lane & 15)) * 64 + ((g ^ vfr) << 4);
  int bofs[4];
  #pragma unroll
  for (int ni = 0; ni < 4; ++ni) {
    int j = wn * 64 + ni * 16 + (lane & 15);
    bofs[ni] = j * 64 + (((2 * g) ^ xorB(j)) << 3);
  }
  f32x4 acc[4][4];
  const f32x4 zz = {0.f, 0.f, 0.f, 0.f};
  #pragma unroll
  for (int mi = 0; mi < 4; ++mi)
    #pragma unroll
    for (int ni = 0; ni < 4; ++ni) acc[mi][ni] = zz;

  for (int kq = 0; kq < 16; ++kq) {
    __syncthreads();
    gl16(a0 + kq * 64, dA0);
    gl16(a1 + kq * 64, dA1);
    gl16(bp0 + (size_t)kq * 4096, dB0);
    gl16(bp1 + (size_t)kq * 4096, dB1);
    __syncthreads();
    bf16x8 af[4];
    #pragma unroll
    for (int mi = 0; mi < 4; ++mi) af[mi] = *(const bf16x8*)(ldsA + aro + mi * 1024);
    #pragma unroll
    for (int ni = 0; ni < 4; ++ni) {
      bf16x4 lo = *(const bf16x4*)(ldsB + bofs[ni]);
      bf16x4 hi = *(const bf16x4*)(ldsB + (bofs[ni] ^ 8));
      bf16x8 bv = __builtin_shufflevector(lo, hi, 0, 1, 2, 3, 4, 5, 6, 7);
      #pragma unroll
      for (int mi = 0; mi < 4; ++mi)
        acc[mi][ni] = __builtin_amdgcn_mfma_f32_16x16x32_bf16(af[mi], bv, acc[mi][ni], 0, 0, 0);
    }
  }
  #pragma unroll
  for (int ni = 0; ni < 4; ++ni) {
    int col = n0 + wn * 64 + ni * 16 + (lane & 15);
    float bb = b2[e * 1024 + col];
    #pragma unroll
    for (int mi = 0; mi < 4; ++mi) {
      int rb = wm * 64 + mi * 16 + ((lane >> 4) << 2);
      #pragma unroll
      for (int r = 0; r < 4; ++r) {
        int row = rb + r;
        if (row < nrem) {
          int gi = off_e + m0 + row;
          atomicAdd(out + (size_t)tok[gi] * 1024 + col, (acc[mi][ni][r] + bb) * wtl[gi]);
        }
      }
    }
  }
}

// ------------------------------------------------------------------ host ----
extern "C" void kernel_launch(void* const* d_in, const int* in_sizes, int n_in,
                              void* d_out, int out_size, void* d_ws, size_t ws_size,
                              hipStream_t stream) {
  const float* x   = (const float*)d_in[0];
  const float* gw  = (const float*)d_in[1];
  const float* gb  = (const float*)d_in[2];
  const float* w1  = (const float*)d_in[3];
  const float* b1  = (const float*)d_in[4];
  const float* w3  = (const float*)d_in[5];
  const float* b3  = (const float*)d_in[6];
  const float* w2  = (const float*)d_in[7];
  const float* b2  = (const float*)d_in[8];
  const float* sw1 = (const float*)d_in[9];
  const float* sb1 = (const float*)d_in[10];
  const float* sw3 = (const float*)d_in[11];
  const float* sb3 = (const float*)d_in[12];
  const float* sw2 = (const float*)d_in[13];
  const float* sb2 = (const float*)d_in[14];
  float* out = (float*)d_out;
  char* ws = (char*)d_ws;

  const size_t OFF_XB   = 134217728;  // H/Hs at 0 (134 MB; Hs aliases low 67 MB)
  const size_t OFF_W1I  = 201326592;
  const size_t OFF_W3I  = 234881024;
  const size_t OFF_W2I  = 268435456;
  const size_t OFF_SW1I = 301989888;
  const size_t OFF_SW3I = 304087040;
  const size_t OFF_SW2I = 306184192;
  const size_t OFF_IDX  = 308281344;
  const size_t OFF_WTS  = 308805632;
  const size_t OFF_TOK  = 309329920;
  const size_t OFF_WTL  = 309854208;
  const size_t OFF_META = 310378496;
  if (ws_size < OFF_META + 8960) return;  // loud failure if ws too small

  unsigned short* H    = (unsigned short*)ws;
  unsigned short* xb   = (unsigned short*)(ws + OFF_XB);
  unsigned short* w1i  = (unsigned short*)(ws + OFF_W1I);
  unsigned short* w3i  = (unsigned short*)(ws + OFF_W3I);
  unsigned short* w2i  = (unsigned short*)(ws + OFF_W2I);
  unsigned short* sw1i = (unsigned short*)(ws + OFF_SW1I);
  unsigned short* sw3i = (unsigned short*)(ws + OFF_SW3I);
  unsigned short* sw2i = (unsigned short*)(ws + OFF_SW2I);
  int*   idx  = (int*)(ws + OFF_IDX);
  float* wts  = (float*)(ws + OFF_WTS);
  int*   tokl = (int*)(ws + OFF_TOK);
  float* wtl  = (float*)(ws + OFF_WTL);
  int*   meta = (int*)(ws + OFF_META);

  hipMemsetAsync(meta, 0, 128, stream);
  gate_kernel<<<dim3(8192), dim3(256), 0, stream>>>(x, gw, gb, idx, wts);
  count_kernel<<<dim3(512), dim3(256), 0, stream>>>(idx, meta);
  scan_kernel<<<dim3(1), dim3(64), 0, stream>>>(meta);
  scatter_kernel<<<dim3(512), dim3(256), 0, stream>>>(idx, wts, meta, tokl, wtl);
  cvt_x_kernel<<<dim3(16384), dim3(256), 0, stream>>>(x, xb);
  repack_kernel<<<dim3(2048), dim3(256), 0, stream>>>(w1, w1i, 1024, 512, 256);
  repack_kernel<<<dim3(2048), dim3(256), 0, stream>>>(w3, w3i, 1024, 512, 256);
  repack_kernel<<<dim3(2048), dim3(256), 0, stream>>>(w2, w2i, 512, 1024, 256);
  repack_kernel<<<dim3(128), dim3(256), 0, stream>>>(sw1, sw1i, 1024, 1024, 512);
  repack_kernel<<<dim3(128), dim3(256), 0, stream>>>(sw3, sw3i, 1024, 1024, 512);
  repack_kernel<<<dim3(128), dim3(256), 0, stream>>>(sw2, sw2i, 1024, 1024, 512);
  s1_kernel<<<dim3(16, 256), dim3(256), 0, stream>>>(xb, sw1i, sw3i, sb1, sb3, H);
  s2_kernel<<<dim3(8, 256), dim3(256), 0, stream>>>(H, sw2i, sb2, out);
  g1_kernel<<<dim3(8, 1056), dim3(256), 0, stream>>>(xb, w1i, w3i, b1, b3, tokl, meta, H);
  g2_kernel<<<dim3(8, 1056), dim3(256), 0, stream>>>(H, w2i, b2, tokl, wtl, meta, out);
}

// Round 3
// 1605.032 us; speedup vs baseline: 1.6218x; 1.1670x over previous
//
#include <hip/hip_runtime.h>
#include <stdint.h>

#define DIM_    1024
#define INTER_  512

typedef short bf16x4 __attribute__((ext_vector_type(4)));
typedef short bf16x8 __attribute__((ext_vector_type(8)));
typedef float f32x4  __attribute__((ext_vector_type(4)));

__device__ __forceinline__ unsigned short f2bf(float f) {
  union { float f; unsigned u; } v; v.f = f;
  return (unsigned short)((v.u + 0x7FFFu + ((v.u >> 16) & 1u)) >> 16);
}
__device__ __forceinline__ unsigned f2bf2(float a, float b) {
  union { float f; unsigned u; } va, vb; va.f = a; vb.f = b;
  unsigned ra = (va.u + 0x7FFFu + ((va.u >> 16) & 1u)) >> 16;
  unsigned rb = (vb.u + 0x7FFFu + ((vb.u >> 16) & 1u)) >> 16;
  return ra | (rb << 16);
}
__device__ __forceinline__ float bfhi(unsigned u) {
  union { unsigned u; float f; } v; v.u = u & 0xffff0000u; return v.f;
}
__device__ __forceinline__ float bflo(unsigned u) {
  union { unsigned u; float f; } v; v.u = u << 16; return v.f;
}
__device__ __forceinline__ int xorB(int j) { return (j & 7) ^ ((j >> 3) & 7); }

__device__ __forceinline__ void gl16(const void* g, void* l) {
  __builtin_amdgcn_global_load_lds(
      (const __attribute__((address_space(1))) unsigned int*)g,
      (__attribute__((address_space(3))) unsigned int*)l, 16, 0, 0);
}

// ---------------------------------------------------------------- gate ----
__global__ __launch_bounds__(256) void gate_kernel(
    const float* __restrict__ x, const float* __restrict__ gw,
    const float* __restrict__ gb, int* __restrict__ idx, float* __restrict__ wts) {
  __shared__ double s_sc[4][32];
  __shared__ double s_gs[4][8];
  const int wid = threadIdx.x >> 6, lane = threadIdx.x & 63;
  const int t = blockIdx.x * 4 + wid;
  const int e = lane & 31, half = lane >> 5;
  const float* xr  = x  + (size_t)t * DIM_ + half * 512;
  const float* gwp = gw + (size_t)half * 512 * 32 + e;
  double a0 = 0, a1 = 0, a2 = 0, a3 = 0;
  for (int k = 0; k < 512; k += 4) {
    float4 xv = *(const float4*)(xr + k);
    a0 += (double)xv.x * (double)gwp[(k + 0) * 32];
    a1 += (double)xv.y * (double)gwp[(k + 1) * 32];
    a2 += (double)xv.z * (double)gwp[(k + 2) * 32];
    a3 += (double)xv.w * (double)gwp[(k + 3) * 32];
  }
  double lg = (a0 + a1) + (a2 + a3);
  lg += __shfl_xor(lg, 32);
  lg += (double)gb[e];
  double m = lg;
  #pragma unroll
  for (int d = 1; d < 32; d <<= 1) m = fmax(m, __shfl_xor(m, d));
  double ex = exp(lg - m);
  double ssum = ex;
  #pragma unroll
  for (int d = 1; d < 32; d <<= 1) ssum += __shfl_xor(ssum, d);
  double sc = ex / ssum;
  double p  = __shfl_xor(sc, 1);
  double m1 = fmax(sc, p), n1 = fmin(sc, p);
  double m2 = __shfl_xor(m1, 2), n2 = __shfl_xor(n1, 2);
  double gs = (m1 >= m2) ? (m1 + fmax(n1, m2)) : (m2 + fmax(n2, m1));
  if (lane < 32) {
    s_sc[wid][e] = sc;
    if ((e & 3) == 0) s_gs[wid][e >> 2] = gs;
  }
  __syncthreads();
  if (lane == 0) {
    unsigned kmask = 0;
    for (int it = 0; it < 4; ++it) {
      int bg = 0; double bv = -1.0;
      for (int g = 0; g < 8; ++g)
        if (!((kmask >> g) & 1u) && s_gs[wid][g] > bv) { bv = s_gs[wid][g]; bg = g; }
      kmask |= 1u << bg;
    }
    unsigned umask = 0;
    for (int slot = 0; slot < 4; ++slot) {
      int be = 0; double bv = -1.0;
      for (int ee = 0; ee < 32; ++ee)
        if (((kmask >> (ee >> 2)) & 1u) && !((umask >> ee) & 1u) && s_sc[wid][ee] > bv) {
          bv = s_sc[wid][ee]; be = ee;
        }
      umask |= 1u << be;
      idx[t * 4 + slot] = be;
      wts[t * 4 + slot] = (float)bv;
    }
  }
}

// ------------------------------------------------- dispatch bookkeeping ----
__global__ __launch_bounds__(256) void count_kernel(const int* __restrict__ idx,
                                                    int* __restrict__ meta) {
  __shared__ int h[32];
  int tid = threadIdx.x;
  if (tid < 32) h[tid] = 0;
  __syncthreads();
  atomicAdd(&h[idx[blockIdx.x * 256 + tid]], 1);
  __syncthreads();
  if (tid < 32 && h[tid]) atomicAdd(&meta[tid], h[tid]);
}

__global__ void scan_kernel(int* __restrict__ meta) {
  int lane = threadIdx.x & 63;
  if (lane < 32) {
    int c = meta[lane];
    int pre = c;
    #pragma unroll
    for (int d = 1; d < 32; d <<= 1) { int t = __shfl_up(pre, d); if (lane >= d) pre += t; }
    int excl = pre - c;
    meta[64 + lane] = excl;
    meta[32 + lane] = excl;
    int nt = (c + 127) >> 7;
    int ntp = nt;
    #pragma unroll
    for (int d = 1; d < 32; d <<= 1) { int t = __shfl_up(ntp, d); if (lane >= d) ntp += t; }
    int ntExcl = ntp - nt;
    for (int k = 0; k < nt; ++k) { meta[128 + ntExcl + k] = lane; meta[1184 + ntExcl + k] = k << 7; }
    if (lane == 31) { meta[96] = excl + c; meta[97] = ntExcl + nt; }
  }
}

__global__ __launch_bounds__(256) void scatter_kernel(
    const int* __restrict__ idx, int* __restrict__ meta,
    int* __restrict__ tok, int* __restrict__ inv) {
  int i = blockIdx.x * 256 + threadIdx.x;
  int lane = threadIdx.x & 63;
  int e = idx[i];
  unsigned long long m = ~0ull;
  #pragma unroll
  for (int b = 0; b < 5; ++b) {
    unsigned long long vote = __ballot((e >> b) & 1);
    m &= ((e >> b) & 1) ? vote : ~vote;
  }
  int leader = __ffsll((long long)m) - 1;
  int rank = __popcll(m & ((1ull << lane) - 1));
  int base = 0;
  if (lane == leader) base = atomicAdd(&meta[32 + e], (int)__popcll(m));
  base = __shfl(base, leader);
  int p = base + rank;
  tok[p] = i >> 2;
  inv[i] = p;
}

// ----------------------------------------------------------- repacking ----
__global__ __launch_bounds__(256) void cvt_x_kernel(const float* __restrict__ x,
                                                    unsigned short* __restrict__ xb) {
  size_t i = ((size_t)blockIdx.x * 256 + threadIdx.x) * 8;
  float4 f0 = *(const float4*)(x + i);
  float4 f1 = *(const float4*)(x + i + 4);
  uint4 o;
  o.x = f2bf2(f0.x, f0.y); o.y = f2bf2(f0.z, f0.w);
  o.z = f2bf2(f1.x, f1.y); o.w = f2bf2(f1.z, f1.w);
  *(uint4*)(xb + i) = o;
}

// weight [e][K][N] fp32 -> bf16 LDS-image tiles (4KB, pre-swizzled).
__global__ __launch_bounds__(256) void repack_kernel(
    const float* __restrict__ src, unsigned short* __restrict__ dst,
    int K, int N, int tilesPerMat) {
  const int w = blockIdx.x * 4 + (threadIdx.x >> 6);
  const int l = threadIdx.x & 63;
  const int e = w / tilesPerMat, rem = w % tilesPerMat;
  const int kSteps = K >> 5;
  const int nt = rem / kSteps, kq = rem % kSteps;
  const float* s = src + (size_t)e * K * N + (size_t)(kq * 32) * N + nt * 64 + l;
  float v[32];
  #pragma unroll
  for (int kk = 0; kk < 32; ++kk) v[kk] = s[(size_t)kk * N];
  char* d = (char*)dst + (size_t)w * 4096 + l * 64;
  const int xb_ = xorB(l);
  #pragma unroll
  for (int q = 0; q < 8; ++q) {
    uint2 o;
    o.x = f2bf2(v[4 * q + 0], v[4 * q + 1]);
    o.y = f2bf2(v[4 * q + 2], v[4 * q + 3]);
    *(uint2*)(d + ((q ^ xb_) << 3)) = o;
  }
}

// --------------------------------------------------------- shared GEMM1 ----
// BM=128 BN=64 BK=32, dual-B, 2-phase LDS double-buffer (stage next, compute
// cur, one __syncthreads per k-step: its vmcnt(0) lands AFTER the compute so
// the staged loads' latency is covered).
__global__ __launch_bounds__(256) void s1_kernel(
    const unsigned short* __restrict__ xb, const unsigned short* __restrict__ b1i,
    const unsigned short* __restrict__ b3i, const float* __restrict__ sb1,
    const float* __restrict__ sb3, unsigned short* __restrict__ Hs) {
  __shared__ char lds[32768];
  const int n0 = blockIdx.x * 64;
  const int m0 = blockIdx.y * 128;
  const int tid = threadIdx.x, lane = tid & 63, wave = tid >> 6;
  const int wm = wave >> 1, wn = wave & 1;

  const int r0 = tid >> 2, s0 = tid & 3;
  const int vrw = (r0 & 3) ^ ((r0 >> 2) & 1);
  const char* a0 = (const char*)xb + (size_t)(m0 + r0) * 2048 + ((s0 ^ vrw) << 4);
  const char* a1 = (const char*)xb + (size_t)(m0 + r0 + 64) * 2048 + ((s0 ^ vrw) << 4);
  const char* b1p = (const char*)b1i + (size_t)(blockIdx.x * 32) * 4096 + tid * 16;
  const char* b3p = (const char*)b3i + (size_t)(blockIdx.x * 32) * 4096 + tid * 16;

  const int g = lane >> 4;
  const int vfr = (lane & 3) ^ ((lane >> 2) & 1);
  const int aro = (wm * 64 + (lane & 15)) * 64 + ((g ^ vfr) << 4);
  int bofs[2];
  #pragma unroll
  for (int ni = 0; ni < 2; ++ni) {
    int j = wn * 32 + ni * 16 + (lane & 15);
    bofs[ni] = j * 64 + (((2 * g) ^ xorB(j)) << 3);
  }

  f32x4 acc1[4][2], acc3[4][2];
  const f32x4 zz = {0.f, 0.f, 0.f, 0.f};
  #pragma unroll
  for (int mi = 0; mi < 4; ++mi)
    #pragma unroll
    for (int ni = 0; ni < 2; ++ni) { acc1[mi][ni] = zz; acc3[mi][ni] = zz; }

  auto stage = [&](int buf, int kq) {
    char* b = lds + buf * 16384;
    gl16(a0 + kq * 64, b + wave * 1024);
    gl16(a1 + kq * 64, b + 4096 + wave * 1024);
    gl16(b1p + (size_t)kq * 4096, b + 8192 + wave * 1024);
    gl16(b3p + (size_t)kq * 4096, b + 12288 + wave * 1024);
  };
  stage(0, 0);
  __syncthreads();
  int cur = 0;
  for (int kq = 0; kq < 32; ++kq) {
    if (kq + 1 < 32) stage(cur ^ 1, kq + 1);
    char* cb = lds + cur * 16384;
    bf16x8 af[4];
    #pragma unroll
    for (int mi = 0; mi < 4; ++mi) af[mi] = *(const bf16x8*)(cb + aro + mi * 1024);
    #pragma unroll
    for (int ni = 0; ni < 2; ++ni) {
      bf16x4 lo = *(const bf16x4*)(cb + 8192 + bofs[ni]);
      bf16x4 hi = *(const bf16x4*)(cb + 8192 + (bofs[ni] ^ 8));
      bf16x8 bv = __builtin_shufflevector(lo, hi, 0, 1, 2, 3, 4, 5, 6, 7);
      #pragma unroll
      for (int mi = 0; mi < 4; ++mi)
        acc1[mi][ni] = __builtin_amdgcn_mfma_f32_16x16x32_bf16(af[mi], bv, acc1[mi][ni], 0, 0, 0);
      bf16x4 lo3 = *(const bf16x4*)(cb + 12288 + bofs[ni]);
      bf16x4 hi3 = *(const bf16x4*)(cb + 12288 + (bofs[ni] ^ 8));
      bf16x8 bv3 = __builtin_shufflevector(lo3, hi3, 0, 1, 2, 3, 4, 5, 6, 7);
      #pragma unroll
      for (int mi = 0; mi < 4; ++mi)
        acc3[mi][ni] = __builtin_amdgcn_mfma_f32_16x16x32_bf16(af[mi], bv3, acc3[mi][ni], 0, 0, 0);
    }
    __syncthreads();
    cur ^= 1;
  }
  #pragma unroll
  for (int ni = 0; ni < 2; ++ni) {
    int col = n0 + wn * 32 + ni * 16 + (lane & 15);
    float bb1 = sb1[col], bb3 = sb3[col];
    #pragma unroll
    for (int mi = 0; mi < 4; ++mi) {
      int rb = wm * 64 + mi * 16 + ((lane >> 4) << 2);
      #pragma unroll
      for (int r = 0; r < 4; ++r) {
        int row = m0 + rb + r;
        float v1 = acc1[mi][ni][r] + bb1;
        float v3 = acc3[mi][ni][r] + bb3;
        float h = (v1 / (1.f + __expf(-v1))) * v3;
        Hs[(size_t)row * 1024 + col] = f2bf(h);
      }
    }
  }
}

// --------------------------------------------------------- shared GEMM2 ----
__global__ __launch_bounds__(256) void s2_kernel(
    const unsigned short* __restrict__ Hs, const unsigned short* __restrict__ b2i,
    const float* __restrict__ sb2, float* __restrict__ out) {
  __shared__ char lds[32768];
  const int n0 = blockIdx.x * 128;
  const int m0 = blockIdx.y * 128;
  const int tid = threadIdx.x, lane = tid & 63, wave = tid >> 6;
  const int wm = wave >> 1, wn = wave & 1;

  const int r0 = tid >> 2, s0 = tid & 3;
  const int vrw = (r0 & 3) ^ ((r0 >> 2) & 1);
  const char* a0 = (const char*)Hs + (size_t)(m0 + r0) * 2048 + ((s0 ^ vrw) << 4);
  const char* a1 = (const char*)Hs + (size_t)(m0 + r0 + 64) * 2048 + ((s0 ^ vrw) << 4);
  const char* bp0 = (const char*)b2i + (size_t)((blockIdx.x * 2 + 0) * 32) * 4096 + tid * 16;
  const char* bp1 = (const char*)b2i + (size_t)((blockIdx.x * 2 + 1) * 32) * 4096 + tid * 16;

  const int g = lane >> 4;
  const int vfr = (lane & 3) ^ ((lane >> 2) & 1);
  const int aro = (wm * 64 + (lane & 15)) * 64 + ((g ^ vfr) << 4);
  int bofs[4];
  #pragma unroll
  for (int ni = 0; ni < 4; ++ni) {
    int j = wn * 64 + ni * 16 + (lane & 15);
    bofs[ni] = j * 64 + (((2 * g) ^ xorB(j)) << 3);
  }
  f32x4 acc[4][4];
  const f32x4 zz = {0.f, 0.f, 0.f, 0.f};
  #pragma unroll
  for (int mi = 0; mi < 4; ++mi)
    #pragma unroll
    for (int ni = 0; ni < 4; ++ni) acc[mi][ni] = zz;

  auto stage = [&](int buf, int kq) {
    char* b = lds + buf * 16384;
    gl16(a0 + kq * 64, b + wave * 1024);
    gl16(a1 + kq * 64, b + 4096 + wave * 1024);
    gl16(bp0 + (size_t)kq * 4096, b + 8192 + wave * 1024);
    gl16(bp1 + (size_t)kq * 4096, b + 12288 + wave * 1024);
  };
  stage(0, 0);
  __syncthreads();
  int cur = 0;
  for (int kq = 0; kq < 32; ++kq) {
    if (kq + 1 < 32) stage(cur ^ 1, kq + 1);
    char* cb = lds + cur * 16384;
    bf16x8 af[4];
    #pragma unroll
    for (int mi = 0; mi < 4; ++mi) af[mi] = *(const bf16x8*)(cb + aro + mi * 1024);
    #pragma unroll
    for (int ni = 0; ni < 4; ++ni) {
      bf16x4 lo = *(const bf16x4*)(cb + 8192 + bofs[ni]);
      bf16x4 hi = *(const bf16x4*)(cb + 8192 + (bofs[ni] ^ 8));
      bf16x8 bv = __builtin_shufflevector(lo, hi, 0, 1, 2, 3, 4, 5, 6, 7);
      #pragma unroll
      for (int mi = 0; mi < 4; ++mi)
        acc[mi][ni] = __builtin_amdgcn_mfma_f32_16x16x32_bf16(af[mi], bv, acc[mi][ni], 0, 0, 0);
    }
    __syncthreads();
    cur ^= 1;
  }
  #pragma unroll
  for (int ni = 0; ni < 4; ++ni) {
    int col = n0 + wn * 64 + ni * 16 + (lane & 15);
    float bb = sb2[col];
    #pragma unroll
    for (int mi = 0; mi < 4; ++mi) {
      int rb = m0 + wm * 64 + mi * 16 + ((lane >> 4) << 2);
      #pragma unroll
      for (int r = 0; r < 4; ++r)
        out[(size_t)(rb + r) * 1024 + col] = acc[mi][ni][r] + bb;
    }
  }
}

// --------------------------------------------------------- routed GEMM1 ----
__global__ __launch_bounds__(256) void g1_kernel(
    const unsigned short* __restrict__ xb, const unsigned short* __restrict__ w1i,
    const unsigned short* __restrict__ w3i, const float* __restrict__ b1,
    const float* __restrict__ b3, const int* __restrict__ tok,
    const int* __restrict__ meta, unsigned short* __restrict__ H) {
  __shared__ char lds[32768];
  if ((int)blockIdx.y >= meta[97]) return;
  const int e = meta[128 + blockIdx.y], m0 = meta[1184 + blockIdx.y];
  const int off_e = meta[64 + e], nrem = meta[e] - m0;
  const int n0 = blockIdx.x * 64;
  const int tid = threadIdx.x, lane = tid & 63, wave = tid >> 6;
  const int wm = wave >> 1, wn = wave & 1;

  const int r0 = tid >> 2, s0 = tid & 3;
  const int vrw = (r0 & 3) ^ ((r0 >> 2) & 1);
  int tr0 = tok[off_e + m0 + ((r0 < nrem) ? r0 : 0)];
  int tr1 = tok[off_e + m0 + ((r0 + 64 < nrem) ? r0 + 64 : 0)];
  const char* a0 = (const char*)xb + (size_t)tr0 * 2048 + ((s0 ^ vrw) << 4);
  const char* a1 = (const char*)xb + (size_t)tr1 * 2048 + ((s0 ^ vrw) << 4);
  const char* b1p = (const char*)w1i + (size_t)((e * 8 + blockIdx.x) * 32) * 4096 + tid * 16;
  const char* b3p = (const char*)w3i + (size_t)((e * 8 + blockIdx.x) * 32) * 4096 + tid * 16;

  const int g = lane >> 4;
  const int vfr = (lane & 3) ^ ((lane >> 2) & 1);
  const int aro = (wm * 64 + (lane & 15)) * 64 + ((g ^ vfr) << 4);
  int bofs[2];
  #pragma unroll
  for (int ni = 0; ni < 2; ++ni) {
    int j = wn * 32 + ni * 16 + (lane & 15);
    bofs[ni] = j * 64 + (((2 * g) ^ xorB(j)) << 3);
  }

  f32x4 acc1[4][2], acc3[4][2];
  const f32x4 zz = {0.f, 0.f, 0.f, 0.f};
  #pragma unroll
  for (int mi = 0; mi < 4; ++mi)
    #pragma unroll
    for (int ni = 0; ni < 2; ++ni) { acc1[mi][ni] = zz; acc3[mi][ni] = zz; }

  auto stage = [&](int buf, int kq) {
    char* b = lds + buf * 16384;
    gl16(a0 + kq * 64, b + wave * 1024);
    gl16(a1 + kq * 64, b + 4096 + wave * 1024);
    gl16(b1p + (size_t)kq * 4096, b + 8192 + wave * 1024);
    gl16(b3p + (size_t)kq * 4096, b + 12288 + wave * 1024);
  };
  stage(0, 0);
  __syncthreads();
  int cur = 0;
  for (int kq = 0; kq < 32; ++kq) {
    if (kq + 1 < 32) stage(cur ^ 1, kq + 1);
    char* cb = lds + cur * 16384;
    bf16x8 af[4];
    #pragma unroll
    for (int mi = 0; mi < 4; ++mi) af[mi] = *(const bf16x8*)(cb + aro + mi * 1024);
    #pragma unroll
    for (int ni = 0; ni < 2; ++ni) {
      bf16x4 lo = *(const bf16x4*)(cb + 8192 + bofs[ni]);
      bf16x4 hi = *(const bf16x4*)(cb + 8192 + (bofs[ni] ^ 8));
      bf16x8 bv = __builtin_shufflevector(lo, hi, 0, 1, 2, 3, 4, 5, 6, 7);
      #pragma unroll
      for (int mi = 0; mi < 4; ++mi)
        acc1[mi][ni] = __builtin_amdgcn_mfma_f32_16x16x32_bf16(af[mi], bv, acc1[mi][ni], 0, 0, 0);
      bf16x4 lo3 = *(const bf16x4*)(cb + 12288 + bofs[ni]);
      bf16x4 hi3 = *(const bf16x4*)(cb + 12288 + (bofs[ni] ^ 8));
      bf16x8 bv3 = __builtin_shufflevector(lo3, hi3, 0, 1, 2, 3, 4, 5, 6, 7);
      #pragma unroll
      for (int mi = 0; mi < 4; ++mi)
        acc3[mi][ni] = __builtin_amdgcn_mfma_f32_16x16x32_bf16(af[mi], bv3, acc3[mi][ni], 0, 0, 0);
    }
    __syncthreads();
    cur ^= 1;
  }
  #pragma unroll
  for (int ni = 0; ni < 2; ++ni) {
    int col = n0 + wn * 32 + ni * 16 + (lane & 15);
    float bb1 = b1[e * 512 + col], bb3 = b3[e * 512 + col];
    #pragma unroll
    for (int mi = 0; mi < 4; ++mi) {
      int rb = wm * 64 + mi * 16 + ((lane >> 4) << 2);
      #pragma unroll
      for (int r = 0; r < 4; ++r) {
        int row = rb + r;
        if (row < nrem) {
          float v1 = acc1[mi][ni][r] + bb1;
          float v3 = acc3[mi][ni][r] + bb3;
          float h = (v1 / (1.f + __expf(-v1))) * v3;
          H[(size_t)(off_e + m0 + row) * 512 + col] = f2bf(h);
        }
      }
    }
  }
}

// --------------------------------------------------------- routed GEMM2 ----
// Y[pos][512] = (H@w2e + b2e) for one column half (cbase). NO atomics.
__global__ __launch_bounds__(256) void g2_kernel(
    const unsigned short* __restrict__ H, const unsigned short* __restrict__ w2i,
    const float* __restrict__ b2, const int* __restrict__ meta,
    unsigned short* __restrict__ Y, int cbase) {
  __shared__ char lds[32768];
  if ((int)blockIdx.y >= meta[97]) return;
  const int e = meta[128 + blockIdx.y], m0 = meta[1184 + blockIdx.y];
  const int off_e = meta[64 + e], nrem = meta[e] - m0;
  const int n0 = cbase + blockIdx.x * 128;
  const int tid = threadIdx.x, lane = tid & 63, wave = tid >> 6;
  const int wm = wave >> 1, wn = wave & 1;

  const int r0 = tid >> 2, s0 = tid & 3;
  const int vrw = (r0 & 3) ^ ((r0 >> 2) & 1);
  const char* a0 = (const char*)H + (size_t)(off_e + m0 + ((r0 < nrem) ? r0 : 0)) * 1024 + ((s0 ^ vrw) << 4);
  const char* a1 = (const char*)H + (size_t)(off_e + m0 + ((r0 + 64 < nrem) ? r0 + 64 : 0)) * 1024 + ((s0 ^ vrw) << 4);
  const int ntb = n0 >> 6;
  const char* bp0 = (const char*)w2i + (size_t)((e * 16 + ntb + 0) * 16) * 4096 + tid * 16;
  const char* bp1 = (const char*)w2i + (size_t)((e * 16 + ntb + 1) * 16) * 4096 + tid * 16;

  const int g = lane >> 4;
  const int vfr = (lane & 3) ^ ((lane >> 2) & 1);
  const int aro = (wm * 64 + (lane & 15)) * 64 + ((g ^ vfr) << 4);
  int bofs[4];
  #pragma unroll
  for (int ni = 0; ni < 4; ++ni) {
    int j = wn * 64 + ni * 16 + (lane & 15);
    bofs[ni] = j * 64 + (((2 * g) ^ xorB(j)) << 3);
  }
  f32x4 acc[4][4];
  const f32x4 zz = {0.f, 0.f, 0.f, 0.f};
  #pragma unroll
  for (int mi = 0; mi < 4; ++mi)
    #pragma unroll
    for (int ni = 0; ni < 4; ++ni) acc[mi][ni] = zz;

  auto stage = [&](int buf, int kq) {
    char* b = lds + buf * 16384;
    gl16(a0 + kq * 64, b + wave * 1024);
    gl16(a1 + kq * 64, b + 4096 + wave * 1024);
    gl16(bp0 + (size_t)kq * 4096, b + 8192 + wave * 1024);
    gl16(bp1 + (size_t)kq * 4096, b + 12288 + wave * 1024);
  };
  stage(0, 0);
  __syncthreads();
  int cur = 0;
  for (int kq = 0; kq < 16; ++kq) {
    if (kq + 1 < 16) stage(cur ^ 1, kq + 1);
    char* cb = lds + cur * 16384;
    bf16x8 af[4];
    #pragma unroll
    for (int mi = 0; mi < 4; ++mi) af[mi] = *(const bf16x8*)(cb + aro + mi * 1024);
    #pragma unroll
    for (int ni = 0; ni < 4; ++ni) {
      bf16x4 lo = *(const bf16x4*)(cb + 8192 + bofs[ni]);
      bf16x4 hi = *(const bf16x4*)(cb + 8192 + (bofs[ni] ^ 8));
      bf16x8 bv = __builtin_shufflevector(lo, hi, 0, 1, 2, 3, 4, 5, 6, 7);
      #pragma unroll
      for (int mi = 0; mi < 4; ++mi)
        acc[mi][ni] = __builtin_amdgcn_mfma_f32_16x16x32_bf16(af[mi], bv, acc[mi][ni], 0, 0, 0);
    }
    __syncthreads();
    cur ^= 1;
  }
  #pragma unroll
  for (int ni = 0; ni < 4; ++ni) {
    int col = n0 + wn * 64 + ni * 16 + (lane & 15);
    float bb = b2[e * 1024 + col];
    int ycol = col - cbase;
    #pragma unroll
    for (int mi = 0; mi < 4; ++mi) {
      int rb = wm * 64 + mi * 16 + ((lane >> 4) << 2);
      #pragma unroll
      for (int r = 0; r < 4; ++r) {
        int row = rb + r;
        if (row < nrem)
          Y[(size_t)(off_e + m0 + row) * 512 + ycol] = f2bf(acc[mi][ni][r] + bb);
      }
    }
  }
}

// ------------------------------------------------------------- combine ----
// out[t][cbase+c] += sum_s wts[t*4+s] * Y[inv[t*4+s]][c]. Fixed slot order ->
// deterministic. 2 tokens/block, 128 threads/token, float4 per thread.
__global__ __launch_bounds__(256) void combine_kernel(
    const unsigned short* __restrict__ Y, const int* __restrict__ inv,
    const float* __restrict__ wts, float* __restrict__ out, int cbase) {
  int t = blockIdx.x * 2 + (threadIdx.x >> 7);
  int c = (threadIdx.x & 127) * 4;
  int4 iv = *(const int4*)(inv + t * 4);
  float4 wv = *(const float4*)(wts + t * 4);
  float* op = out + (size_t)t * 1024 + cbase + c;
  float4 o = *(float4*)op;
  uint2 u;
  u = *(const uint2*)(Y + (size_t)iv.x * 512 + c);
  o.x += wv.x * bflo(u.x); o.y += wv.x * bfhi(u.x);
  o.z += wv.x * bflo(u.y); o.w += wv.x * bfhi(u.y);
  u = *(const uint2*)(Y + (size_t)iv.y * 512 + c);
  o.x += wv.y * bflo(u.x); o.y += wv.y * bfhi(u.x);
  o.z += wv.y * bflo(u.y); o.w += wv.y * bfhi(u.y);
  u = *(const uint2*)(Y + (size_t)iv.z * 512 + c);
  o.x += wv.z * bflo(u.x); o.y += wv.z * bfhi(u.x);
  o.z += wv.z * bflo(u.y); o.w += wv.z * bfhi(u.y);
  u = *(const uint2*)(Y + (size_t)iv.w * 512 + c);
  o.x += wv.w * bflo(u.x); o.y += wv.w * bfhi(u.x);
  o.z += wv.w * bflo(u.y); o.w += wv.w * bfhi(u.y);
  *(float4*)op = o;
}

// ------------------------------------------------------------------ host ----
extern "C" void kernel_launch(void* const* d_in, const int* in_sizes, int n_in,
                              void* d_out, int out_size, void* d_ws, size_t ws_size,
                              hipStream_t stream) {
  const float* x   = (const float*)d_in[0];
  const float* gw  = (const float*)d_in[1];
  const float* gb  = (const float*)d_in[2];
  const float* w1  = (const float*)d_in[3];
  const float* b1  = (const float*)d_in[4];
  const float* w3  = (const float*)d_in[5];
  const float* b3  = (const float*)d_in[6];
  const float* w2  = (const float*)d_in[7];
  const float* b2  = (const float*)d_in[8];
  const float* sw1 = (const float*)d_in[9];
  const float* sb1 = (const float*)d_in[10];
  const float* sw3 = (const float*)d_in[11];
  const float* sb3 = (const float*)d_in[12];
  const float* sw2 = (const float*)d_in[13];
  const float* sb2 = (const float*)d_in[14];
  float* out = (float*)d_out;
  char* ws = (char*)d_ws;

  // [0,134M): H (g1 out; also s1's Hs 67M alias)
  // [134M,268M): xb(67M)+w1i(32M)+w3i(32M) -- dead after g1, reused as Y(134M)
  const size_t OFF_XB   = 134217728;
  const size_t OFF_W1I  = 201326592;
  const size_t OFF_W3I  = 234881024;
  const size_t OFF_W2I  = 268435456;
  const size_t OFF_SW1I = 301989888;
  const size_t OFF_SW3I = 304087040;
  const size_t OFF_SW2I = 306184192;
  const size_t OFF_IDX  = 308281344;
  const size_t OFF_WTS  = 308805632;
  const size_t OFF_TOK  = 309329920;
  const size_t OFF_INV  = 309854208;
  const size_t OFF_META = 310378496;
  if (ws_size < OFF_META + 8960) return;

  unsigned short* H    = (unsigned short*)ws;
  unsigned short* xb   = (unsigned short*)(ws + OFF_XB);
  unsigned short* Yb   = (unsigned short*)(ws + OFF_XB);   // aliases xb/w1i/w3i
  unsigned short* w1i  = (unsigned short*)(ws + OFF_W1I);
  unsigned short* w3i  = (unsigned short*)(ws + OFF_W3I);
  unsigned short* w2i  = (unsigned short*)(ws + OFF_W2I);
  unsigned short* sw1i = (unsigned short*)(ws + OFF_SW1I);
  unsigned short* sw3i = (unsigned short*)(ws + OFF_SW3I);
  unsigned short* sw2i = (unsigned short*)(ws + OFF_SW2I);
  int*   idx  = (int*)(ws + OFF_IDX);
  float* wts  = (float*)(ws + OFF_WTS);
  int*   tokl = (int*)(ws + OFF_TOK);
  int*   inv  = (int*)(ws + OFF_INV);
  int*   meta = (int*)(ws + OFF_META);

  hipMemsetAsync(meta, 0, 128, stream);
  gate_kernel<<<dim3(8192), dim3(256), 0, stream>>>(x, gw, gb, idx, wts);
  count_kernel<<<dim3(512), dim3(256), 0, stream>>>(idx, meta);
  scan_kernel<<<dim3(1), dim3(64), 0, stream>>>(meta);
  scatter_kernel<<<dim3(512), dim3(256), 0, stream>>>(idx, meta, tokl, inv);
  cvt_x_kernel<<<dim3(16384), dim3(256), 0, stream>>>(x, xb);
  repack_kernel<<<dim3(2048), dim3(256), 0, stream>>>(w1, w1i, 1024, 512, 256);
  repack_kernel<<<dim3(2048), dim3(256), 0, stream>>>(w3, w3i, 1024, 512, 256);
  repack_kernel<<<dim3(2048), dim3(256), 0, stream>>>(w2, w2i, 512, 1024, 256);
  repack_kernel<<<dim3(128), dim3(256), 0, stream>>>(sw1, sw1i, 1024, 1024, 512);
  repack_kernel<<<dim3(128), dim3(256), 0, stream>>>(sw3, sw3i, 1024, 1024, 512);
  repack_kernel<<<dim3(128), dim3(256), 0, stream>>>(sw2, sw2i, 1024, 1024, 512);
  s1_kernel<<<dim3(16, 256), dim3(256), 0, stream>>>(xb, sw1i, sw3i, sb1, sb3, H);
  s2_kernel<<<dim3(8, 256), dim3(256), 0, stream>>>(H, sw2i, sb2, out);
  g1_kernel<<<dim3(8, 1056), dim3(256), 0, stream>>>(xb, w1i, w3i, b1, b3, tokl, meta, H);
  // column-half 0: Y overwrites dead xb/w1i/w3i region
  g2_kernel<<<dim3(4, 1056), dim3(256), 0, stream>>>(H, w2i, b2, meta, Yb, 0);
  combine_kernel<<<dim3(16384), dim3(256), 0, stream>>>(Yb, inv, wts, out, 0);
  // column-half 1
  g2_kernel<<<dim3(4, 1056), dim3(256), 0, stream>>>(H, w2i, b2, meta, Yb, 512);
  combine_kernel<<<dim3(16384), dim3(256), 0, stream>>>(Yb, inv, wts, out, 512);
}